// Round 1
// baseline (1588.254 us; speedup 1.0000x reference)
//
#include <hip/hip_runtime.h>
#include <hip/hip_fp16.h>
#include <cmath>

#define T_TOKENS 8192
#define HID 2048
#define NEXP 8
#define INTERM 1024

typedef _Float16 f16x8 __attribute__((ext_vector_type(8)));
typedef _Float16 f16x4 __attribute__((ext_vector_type(4)));
typedef float f32x4 __attribute__((ext_vector_type(4)));

static __device__ __forceinline__ float gelu_tanh(float v) {
    return 0.5f * v * (1.0f + tanhf(0.79788456080286535588f * (v + 0.044715f * v * v * v)));
}

// ---------------- fp32 -> fp16 elementwise convert ----------------
__global__ void cvt_kernel(const float* __restrict__ in, _Float16* __restrict__ out, int n4) {
    int i = blockIdx.x * blockDim.x + threadIdx.x;
    int stride = gridDim.x * blockDim.x;
    for (; i < n4; i += stride) {
        float4 v = reinterpret_cast<const float4*>(in)[i];
        f16x4 o;
        o[0] = (_Float16)v.x; o[1] = (_Float16)v.y; o[2] = (_Float16)v.z; o[3] = (_Float16)v.w;
        reinterpret_cast<f16x4*>(out)[i] = o;
    }
}

// ------------- fp32 [Z][R][C] -> fp16 [Z][C][R] transpose-convert -------------
__global__ __launch_bounds__(256) void tconv_kernel(const float* __restrict__ in,
                                                    _Float16* __restrict__ out,
                                                    int R, int C) {
    __shared__ float t[32][33];
    int z = blockIdx.z;
    int r0 = blockIdx.y * 32, c0 = blockIdx.x * 32;
    int tid = threadIdx.x;
    int r = tid >> 3, c4 = (tid & 7) * 4;
    const float4 v = *reinterpret_cast<const float4*>(&in[((size_t)z * R + (r0 + r)) * C + c0 + c4]);
    t[r][c4 + 0] = v.x; t[r][c4 + 1] = v.y; t[r][c4 + 2] = v.z; t[r][c4 + 3] = v.w;
    __syncthreads();
    int oc = tid >> 3;          // original col 0..31
    int or4 = (tid & 7) * 4;    // original row start
    f16x4 o;
    o[0] = (_Float16)t[or4 + 0][oc];
    o[1] = (_Float16)t[or4 + 1][oc];
    o[2] = (_Float16)t[or4 + 2][oc];
    o[3] = (_Float16)t[or4 + 3][oc];
    *reinterpret_cast<f16x4*>(&out[((size_t)z * C + (c0 + oc)) * R + r0 + or4]) = o;
}

// ---------------- gating: logits, softmax, top-2, aux stats ----------------
__global__ __launch_bounds__(256) void gate_kernel(const float* __restrict__ x,
                                                   const float* __restrict__ gw,
                                                   int* __restrict__ tk_idx, float* __restrict__ tk_w,
                                                   int* __restrict__ cnt, float* __restrict__ sumP) {
    int gt = (int)((blockIdx.x * blockDim.x + threadIdx.x) >> 6);
    int lane = threadIdx.x & 63;
    if (gt >= T_TOKENS) return;
    const float* xr = x + (size_t)gt * HID;
    float xv[32];
#pragma unroll
    for (int i = 0; i < 32; i++) xv[i] = xr[i * 64 + lane];
    double lg[NEXP];
#pragma unroll
    for (int e = 0; e < NEXP; e++) {
        const float* g = gw + e * HID;
        double s = 0.0;
#pragma unroll
        for (int i = 0; i < 32; i++) s += (double)xv[i] * (double)g[i * 64 + lane];
#pragma unroll
        for (int off = 32; off > 0; off >>= 1) s += __shfl_xor(s, off, 64);
        lg[e] = s;
    }
    if (lane != 0) return;
    double mx = lg[0];
    for (int e = 1; e < NEXP; e++) mx = lg[e] > mx ? lg[e] : mx;
    double ex[NEXP];
    double sum = 0.0;
    for (int e = 0; e < NEXP; e++) { ex[e] = exp(lg[e] - mx); sum += ex[e]; }
    int i0 = 0;
    for (int e = 1; e < NEXP; e++) if (ex[e] > ex[i0]) i0 = e;
    int i1 = (i0 == 0) ? 1 : 0;
    for (int e = 0; e < NEXP; e++) if (e != i0 && ex[e] > ex[i1]) i1 = e;
    double p0 = ex[i0], p1 = ex[i1];
    double t2 = p0 + p1;
    tk_idx[2 * gt] = i0; tk_idx[2 * gt + 1] = i1;
    tk_w[2 * gt] = (float)(p0 / t2); tk_w[2 * gt + 1] = (float)(p1 / t2);
    atomicAdd(&cnt[i0], 1); atomicAdd(&cnt[i1], 1);
    for (int e = 0; e < NEXP; e++) atomicAdd(&sumP[e], (float)(ex[e] / sum));
}

// ---------------- offsets scan + aux loss ----------------
__global__ void finalize_kernel(const int* __restrict__ cnt, const float* __restrict__ sumP,
                                int* __restrict__ offs, float* __restrict__ aux_out) {
    if (threadIdx.x == 0 && blockIdx.x == 0) {
        int off = 0;
        for (int e = 0; e < NEXP; e++) { offs[e] = off; off += cnt[e]; }
        float aux = 0.f;
        for (int e = 0; e < NEXP; e++)
            aux += ((float)cnt[e] / (float)T_TOKENS) * (sumP[e] / (float)T_TOKENS);
        aux_out[0] = 0.01f * (float)NEXP * aux;
    }
}

// ---------------- build per-expert row lists ----------------
__global__ void scatter_kernel(const int* __restrict__ tk_idx, const float* __restrict__ tk_w,
                               const int* __restrict__ offs, int* __restrict__ cursor,
                               int* __restrict__ row_tok, float* __restrict__ row_w) {
    int t = blockIdx.x * blockDim.x + threadIdx.x;
    if (t >= T_TOKENS) return;
    for (int k = 0; k < 2; k++) {
        int e = tk_idx[2 * t + k];
        int pos = atomicAdd(&cursor[e], 1);
        int r = offs[e] + pos;
        row_tok[r] = t;
        row_w[r] = tk_w[2 * t + k];
    }
}

// ---------------- GEMM1: h = gelu(Xe @ W1[e]) ----------------
__global__ __launch_bounds__(256) void gemm1_kernel(const _Float16* __restrict__ xh,
                                                    const _Float16* __restrict__ w1t,
                                                    const int* __restrict__ cnt, const int* __restrict__ offs,
                                                    const int* __restrict__ row_tok,
                                                    _Float16* __restrict__ hh) {
    int e = blockIdx.z;
    int Ne = cnt[e];
    int m0 = blockIdx.y * 64;
    if (m0 >= Ne) return;
    int base = offs[e];
    int n0 = blockIdx.x * 64;
    __shared__ __align__(16) _Float16 As[64][40];
    __shared__ __align__(16) _Float16 Bs[64][40];
    int tid = threadIdx.x;
    int lane = tid & 63;
    int w = tid >> 6, wm = w >> 1, wn = w & 1;
    int sr = tid >> 2, sc = (tid & 3) * 8;
    int arow = m0 + sr; if (arow >= Ne) arow = Ne - 1;
    int tok = row_tok[base + arow];
    const _Float16* aSrc = xh + (size_t)tok * HID + sc;
    const _Float16* bSrc = w1t + ((size_t)e * INTERM + (n0 + sr)) * HID + sc;
    f32x4 acc[2][2] = {};
    int fr = lane & 15;
    int fk = (lane >> 4) * 8;
    for (int k0 = 0; k0 < HID; k0 += 32) {
        *reinterpret_cast<f16x8*>(&As[sr][sc]) = *reinterpret_cast<const f16x8*>(aSrc + k0);
        *reinterpret_cast<f16x8*>(&Bs[sr][sc]) = *reinterpret_cast<const f16x8*>(bSrc + k0);
        __syncthreads();
        f16x8 a0 = *reinterpret_cast<const f16x8*>(&As[wm * 32 + fr][fk]);
        f16x8 a1 = *reinterpret_cast<const f16x8*>(&As[wm * 32 + 16 + fr][fk]);
        f16x8 b0 = *reinterpret_cast<const f16x8*>(&Bs[wn * 32 + fr][fk]);
        f16x8 b1 = *reinterpret_cast<const f16x8*>(&Bs[wn * 32 + 16 + fr][fk]);
        acc[0][0] = __builtin_amdgcn_mfma_f32_16x16x32_f16(a0, b0, acc[0][0], 0, 0, 0);
        acc[0][1] = __builtin_amdgcn_mfma_f32_16x16x32_f16(a0, b1, acc[0][1], 0, 0, 0);
        acc[1][0] = __builtin_amdgcn_mfma_f32_16x16x32_f16(a1, b0, acc[1][0], 0, 0, 0);
        acc[1][1] = __builtin_amdgcn_mfma_f32_16x16x32_f16(a1, b1, acc[1][1], 0, 0, 0);
        __syncthreads();
    }
    int rbase = (lane >> 4) * 4;
#pragma unroll
    for (int mi = 0; mi < 2; mi++) {
#pragma unroll
        for (int r = 0; r < 4; r++) {
            int row = m0 + wm * 32 + mi * 16 + rbase + r;
            if (row < Ne) {
#pragma unroll
                for (int ni = 0; ni < 2; ni++) {
                    float v = gelu_tanh(acc[mi][ni][r]);
                    hh[(size_t)(base + row) * INTERM + n0 + wn * 32 + ni * 16 + fr] = (_Float16)v;
                }
            }
        }
    }
}

// ---------------- GEMM2: out[token] += w * (h @ W2[e]) ----------------
__global__ __launch_bounds__(256) void gemm2_kernel(const _Float16* __restrict__ hh,
                                                    const _Float16* __restrict__ w2t,
                                                    const int* __restrict__ cnt, const int* __restrict__ offs,
                                                    const int* __restrict__ row_tok, const float* __restrict__ row_w,
                                                    float* __restrict__ out) {
    int e = blockIdx.z;
    int Ne = cnt[e];
    int m0 = blockIdx.y * 64;
    if (m0 >= Ne) return;
    int base = offs[e];
    int n0 = blockIdx.x * 64;
    __shared__ __align__(16) _Float16 As[64][40];
    __shared__ __align__(16) _Float16 Bs[64][40];
    int tid = threadIdx.x;
    int lane = tid & 63;
    int w = tid >> 6, wm = w >> 1, wn = w & 1;
    int sr = tid >> 2, sc = (tid & 3) * 8;
    int arow = m0 + sr; if (arow >= Ne) arow = Ne - 1;
    const _Float16* aSrc = hh + (size_t)(base + arow) * INTERM + sc;
    const _Float16* bSrc = w2t + ((size_t)e * HID + (n0 + sr)) * INTERM + sc;
    f32x4 acc[2][2] = {};
    int fr = lane & 15;
    int fk = (lane >> 4) * 8;
    for (int k0 = 0; k0 < INTERM; k0 += 32) {
        *reinterpret_cast<f16x8*>(&As[sr][sc]) = *reinterpret_cast<const f16x8*>(aSrc + k0);
        *reinterpret_cast<f16x8*>(&Bs[sr][sc]) = *reinterpret_cast<const f16x8*>(bSrc + k0);
        __syncthreads();
        f16x8 a0 = *reinterpret_cast<const f16x8*>(&As[wm * 32 + fr][fk]);
        f16x8 a1 = *reinterpret_cast<const f16x8*>(&As[wm * 32 + 16 + fr][fk]);
        f16x8 b0 = *reinterpret_cast<const f16x8*>(&Bs[wn * 32 + fr][fk]);
        f16x8 b1 = *reinterpret_cast<const f16x8*>(&Bs[wn * 32 + 16 + fr][fk]);
        acc[0][0] = __builtin_amdgcn_mfma_f32_16x16x32_f16(a0, b0, acc[0][0], 0, 0, 0);
        acc[0][1] = __builtin_amdgcn_mfma_f32_16x16x32_f16(a0, b1, acc[0][1], 0, 0, 0);
        acc[1][0] = __builtin_amdgcn_mfma_f32_16x16x32_f16(a1, b0, acc[1][0], 0, 0, 0);
        acc[1][1] = __builtin_amdgcn_mfma_f32_16x16x32_f16(a1, b1, acc[1][1], 0, 0, 0);
        __syncthreads();
    }
    int rbase = (lane >> 4) * 4;
#pragma unroll
    for (int mi = 0; mi < 2; mi++) {
#pragma unroll
        for (int r = 0; r < 4; r++) {
            int row = m0 + wm * 32 + mi * 16 + rbase + r;
            if (row < Ne) {
                int tok = row_tok[base + row];
                float wgt = row_w[base + row];
#pragma unroll
                for (int ni = 0; ni < 2; ni++) {
                    atomicAdd(&out[(size_t)tok * HID + n0 + wn * 32 + ni * 16 + fr],
                              wgt * acc[mi][ni][r]);
                }
            }
        }
    }
}

extern "C" void kernel_launch(void* const* d_in, const int* in_sizes, int n_in,
                              void* d_out, int out_size, void* d_ws, size_t ws_size,
                              hipStream_t stream) {
    const float* x  = (const float*)d_in[0];
    const float* gw = (const float*)d_in[1];
    const float* w1 = (const float*)d_in[2];
    const float* w2 = (const float*)d_in[3];
    float* out = (float*)d_out;
    char* ws = (char*)d_ws;

    int*   cnt     = (int*)(ws + 0);
    float* sumP    = (float*)(ws + 32);
    int*   cursor  = (int*)(ws + 64);
    int*   offs    = (int*)(ws + 96);
    int*   row_tok = (int*)(ws + 256);
    float* row_w   = (float*)(ws + 256 + 65536);
    int*   tk_idx  = (int*)(ws + 256 + 2 * 65536);
    float* tk_w    = (float*)(ws + 256 + 3 * 65536);
    _Float16* xh  = (_Float16*)(ws + 262400);
    _Float16* w1t = (_Float16*)(ws + 262400 + 1ull * 33554432);
    _Float16* w2t = (_Float16*)(ws + 262400 + 2ull * 33554432);
    _Float16* hh  = (_Float16*)(ws + 262400 + 3ull * 33554432);

    hipMemsetAsync(d_out, 0, (size_t)out_size * sizeof(float), stream);
    hipMemsetAsync(ws, 0, 128, stream);

    cvt_kernel<<<2048, 256, 0, stream>>>(x, xh, T_TOKENS * HID / 4);
    dim3 g1(INTERM / 32, HID / 32, NEXP);
    tconv_kernel<<<g1, 256, 0, stream>>>(w1, w1t, HID, INTERM);   // w1t[e][i][h]
    dim3 g2(HID / 32, INTERM / 32, NEXP);
    tconv_kernel<<<g2, 256, 0, stream>>>(w2, w2t, INTERM, HID);   // w2t[e][h][i]

    gate_kernel<<<T_TOKENS / 4, 256, 0, stream>>>(x, gw, tk_idx, tk_w, cnt, sumP);
    finalize_kernel<<<1, 64, 0, stream>>>(cnt, sumP, offs, out + (size_t)T_TOKENS * HID);
    scatter_kernel<<<T_TOKENS / 256, 256, 0, stream>>>(tk_idx, tk_w, offs, cursor, row_tok, row_w);

    dim3 gg1(INTERM / 64, 128, NEXP);
    gemm1_kernel<<<gg1, 256, 0, stream>>>(xh, w1t, cnt, offs, row_tok, hh);
    dim3 gg2(HID / 64, 128, NEXP);
    gemm2_kernel<<<gg2, 256, 0, stream>>>(hh, w2t, cnt, offs, row_tok, row_w, out);
}

// Round 2
// 712.954 us; speedup vs baseline: 2.2277x; 2.2277x over previous
//
#include <hip/hip_runtime.h>
#include <hip/hip_fp16.h>
#include <cmath>

#define T_TOKENS 8192
#define HID 2048
#define NEXP 8
#define INTERM 1024
#define GATE_BLOCKS 256

typedef _Float16 f16x8 __attribute__((ext_vector_type(8)));
typedef _Float16 f16x4 __attribute__((ext_vector_type(4)));
typedef float f32x4 __attribute__((ext_vector_type(4)));

static __device__ __forceinline__ float gelu_tanh(float v) {
    return 0.5f * v * (1.0f + tanhf(0.79788456080286535588f * (v + 0.044715f * v * v * v)));
}

// ---------------- fp32 -> fp16 elementwise convert ----------------
__global__ void cvt_kernel(const float* __restrict__ in, _Float16* __restrict__ out, int n4) {
    int i = blockIdx.x * blockDim.x + threadIdx.x;
    int stride = gridDim.x * blockDim.x;
    for (; i < n4; i += stride) {
        float4 v = reinterpret_cast<const float4*>(in)[i];
        f16x4 o;
        o[0] = (_Float16)v.x; o[1] = (_Float16)v.y; o[2] = (_Float16)v.z; o[3] = (_Float16)v.w;
        reinterpret_cast<f16x4*>(out)[i] = o;
    }
}

// ------------- fp32 [Z][R][C] -> fp16 [Z][C][R] transpose-convert -------------
__global__ __launch_bounds__(256) void tconv_kernel(const float* __restrict__ in,
                                                    _Float16* __restrict__ out,
                                                    int R, int C) {
    __shared__ float t[32][33];
    int z = blockIdx.z;
    int r0 = blockIdx.y * 32, c0 = blockIdx.x * 32;
    int tid = threadIdx.x;
    int r = tid >> 3, c4 = (tid & 7) * 4;
    const float4 v = *reinterpret_cast<const float4*>(&in[((size_t)z * R + (r0 + r)) * C + c0 + c4]);
    t[r][c4 + 0] = v.x; t[r][c4 + 1] = v.y; t[r][c4 + 2] = v.z; t[r][c4 + 3] = v.w;
    __syncthreads();
    int oc = tid >> 3;          // original col 0..31
    int or4 = (tid & 7) * 4;    // original row start
    f16x4 o;
    o[0] = (_Float16)t[or4 + 0][oc];
    o[1] = (_Float16)t[or4 + 1][oc];
    o[2] = (_Float16)t[or4 + 2][oc];
    o[3] = (_Float16)t[or4 + 3][oc];
    *reinterpret_cast<f16x4*>(&out[((size_t)z * C + (c0 + oc)) * R + r0 + or4]) = o;
}

// ---------------- gating: logits, softmax, top-2, per-block partial stats ----------------
// No global atomics: each block writes its partial cnt/sumP to part_cnt/part_sumP.
__global__ __launch_bounds__(256) void gate_kernel(const float* __restrict__ x,
                                                   const float* __restrict__ gw,
                                                   int* __restrict__ tk_idx, float* __restrict__ tk_w,
                                                   int* __restrict__ part_cnt,      // [NEXP][GATE_BLOCKS]
                                                   double* __restrict__ part_sumP)  // [NEXP][GATE_BLOCKS]
{
    __shared__ double sdsum[4][NEXP];
    __shared__ int scnt[4][NEXP];
    int w = threadIdx.x >> 6;
    int lane = threadIdx.x & 63;
    int wid = blockIdx.x * 4 + w;
    const int nwaves = GATE_BLOCKS * 4;

    double asum[NEXP];
    int acnt[NEXP];
#pragma unroll
    for (int e = 0; e < NEXP; e++) { asum[e] = 0.0; acnt[e] = 0; }

    for (int gt = wid; gt < T_TOKENS; gt += nwaves) {
        const float* xr = x + (size_t)gt * HID;
        float xv[32];
#pragma unroll
        for (int i = 0; i < 32; i++) xv[i] = xr[i * 64 + lane];
        double lg[NEXP];
#pragma unroll
        for (int e = 0; e < NEXP; e++) {
            const float* g = gw + e * HID;
            double s = 0.0;
#pragma unroll
            for (int i = 0; i < 32; i++) s += (double)xv[i] * (double)g[i * 64 + lane];
#pragma unroll
            for (int off = 32; off > 0; off >>= 1) s += __shfl_xor(s, off, 64);
            lg[e] = s;   // full butterfly: all lanes hold the sum
        }
        // softmax + top-2 computed redundantly on all lanes (uniform values)
        double mx = lg[0];
#pragma unroll
        for (int e = 1; e < NEXP; e++) mx = lg[e] > mx ? lg[e] : mx;
        double ex[NEXP];
        double sum = 0.0;
#pragma unroll
        for (int e = 0; e < NEXP; e++) { ex[e] = exp(lg[e] - mx); sum += ex[e]; }
        int i0 = 0;
#pragma unroll
        for (int e = 1; e < NEXP; e++) if (ex[e] > ex[i0]) i0 = e;
        int i1 = (i0 == 0) ? 1 : 0;
#pragma unroll
        for (int e = 0; e < NEXP; e++) if (e != i0 && ex[e] > ex[i1]) i1 = e;
        double p0 = ex[i0], p1 = ex[i1];
        double t2 = p0 + p1;
        if (lane == 0) {
            tk_idx[2 * gt] = i0; tk_idx[2 * gt + 1] = i1;
            tk_w[2 * gt] = (float)(p0 / t2); tk_w[2 * gt + 1] = (float)(p1 / t2);
        }
#pragma unroll
        for (int e = 0; e < NEXP; e++) {
            asum[e] += ex[e] / sum;
            acnt[e] += (e == i0 ? 1 : 0) + (e == i1 ? 1 : 0);
        }
    }
    if (lane == 0) {
#pragma unroll
        for (int e = 0; e < NEXP; e++) { sdsum[w][e] = asum[e]; scnt[w][e] = acnt[e]; }
    }
    __syncthreads();
    if (threadIdx.x < NEXP) {
        int e = threadIdx.x;
        double s = sdsum[0][e] + sdsum[1][e] + sdsum[2][e] + sdsum[3][e];
        int c = scnt[0][e] + scnt[1][e] + scnt[2][e] + scnt[3][e];
        part_sumP[e * GATE_BLOCKS + blockIdx.x] = s;
        part_cnt[e * GATE_BLOCKS + blockIdx.x] = c;
    }
}

// ---------------- reduce partials, offsets scan, aux loss, zero cursor ----------------
__global__ __launch_bounds__(256) void finalize_kernel(const int* __restrict__ part_cnt,
                                                       const double* __restrict__ part_sumP,
                                                       int* __restrict__ cnt, int* __restrict__ offs,
                                                       int* __restrict__ cursor,
                                                       float* __restrict__ aux_out) {
    __shared__ double sE[NEXP];
    __shared__ int cE[NEXP];
    int w = threadIdx.x >> 6;
    int lane = threadIdx.x & 63;
#pragma unroll
    for (int j = 0; j < 2; j++) {
        int e = w * 2 + j;
        double s = part_sumP[e * GATE_BLOCKS + lane]
                 + part_sumP[e * GATE_BLOCKS + lane + 64]
                 + part_sumP[e * GATE_BLOCKS + lane + 128]
                 + part_sumP[e * GATE_BLOCKS + lane + 192];
        int c = part_cnt[e * GATE_BLOCKS + lane]
              + part_cnt[e * GATE_BLOCKS + lane + 64]
              + part_cnt[e * GATE_BLOCKS + lane + 128]
              + part_cnt[e * GATE_BLOCKS + lane + 192];
#pragma unroll
        for (int off = 32; off > 0; off >>= 1) {
            s += __shfl_xor(s, off, 64);
            c += __shfl_xor(c, off, 64);
        }
        if (lane == 0) { sE[e] = s; cE[e] = c; }
    }
    __syncthreads();
    if (threadIdx.x == 0) {
        int off = 0;
        double aux = 0.0;
#pragma unroll
        for (int e = 0; e < NEXP; e++) {
            cnt[e] = cE[e];
            offs[e] = off;
            off += cE[e];
            cursor[e] = 0;
            aux += ((double)cE[e] / (double)T_TOKENS) * (sE[e] / (double)T_TOKENS);
        }
        aux_out[0] = (float)(0.01 * (double)NEXP * aux);
    }
}

// ---------------- build per-expert row lists (wave-aggregated atomics) ----------------
__global__ void scatter_kernel(const int* __restrict__ tk_idx, const float* __restrict__ tk_w,
                               const int* __restrict__ offs, int* __restrict__ cursor,
                               int* __restrict__ row_tok, float* __restrict__ row_w) {
    int t = blockIdx.x * blockDim.x + threadIdx.x;
    int lane = threadIdx.x & 63;
    unsigned long long below = (lane == 0) ? 0ull : ((~0ull) >> (64 - lane));
    for (int k = 0; k < 2; k++) {
        int e = tk_idx[2 * t + k];
        float wv = tk_w[2 * t + k];
        int pos = 0;
#pragma unroll
        for (int ee = 0; ee < NEXP; ee++) {
            unsigned long long m = __ballot(e == ee);
            if (e == ee) {
                int rank = (int)__popcll(m & below);
                int leader = (int)__ffsll((unsigned long long)m) - 1;
                int base = 0;
                if (lane == leader) base = atomicAdd(&cursor[ee], (int)__popcll(m));
                base = __shfl(base, leader, 64);
                pos = base + rank;
            }
        }
        int r = offs[e] + pos;
        row_tok[r] = t;
        row_w[r] = wv;
    }
}

// ---------------- GEMM1: h = gelu(Xe @ W1[e]) ----------------
__global__ __launch_bounds__(256) void gemm1_kernel(const _Float16* __restrict__ xh,
                                                    const _Float16* __restrict__ w1t,
                                                    const int* __restrict__ cnt, const int* __restrict__ offs,
                                                    const int* __restrict__ row_tok,
                                                    _Float16* __restrict__ hh) {
    int e = blockIdx.z;
    int Ne = cnt[e];
    int m0 = blockIdx.y * 64;
    if (m0 >= Ne) return;
    int base = offs[e];
    int n0 = blockIdx.x * 64;
    __shared__ __align__(16) _Float16 As[64][40];
    __shared__ __align__(16) _Float16 Bs[64][40];
    int tid = threadIdx.x;
    int lane = tid & 63;
    int w = tid >> 6, wm = w >> 1, wn = w & 1;
    int sr = tid >> 2, sc = (tid & 3) * 8;
    int arow = m0 + sr; if (arow >= Ne) arow = Ne - 1;
    int tok = row_tok[base + arow];
    const _Float16* aSrc = xh + (size_t)tok * HID + sc;
    const _Float16* bSrc = w1t + ((size_t)e * INTERM + (n0 + sr)) * HID + sc;
    f32x4 acc[2][2] = {};
    int fr = lane & 15;
    int fk = (lane >> 4) * 8;
    for (int k0 = 0; k0 < HID; k0 += 32) {
        *reinterpret_cast<f16x8*>(&As[sr][sc]) = *reinterpret_cast<const f16x8*>(aSrc + k0);
        *reinterpret_cast<f16x8*>(&Bs[sr][sc]) = *reinterpret_cast<const f16x8*>(bSrc + k0);
        __syncthreads();
        f16x8 a0 = *reinterpret_cast<const f16x8*>(&As[wm * 32 + fr][fk]);
        f16x8 a1 = *reinterpret_cast<const f16x8*>(&As[wm * 32 + 16 + fr][fk]);
        f16x8 b0 = *reinterpret_cast<const f16x8*>(&Bs[wn * 32 + fr][fk]);
        f16x8 b1 = *reinterpret_cast<const f16x8*>(&Bs[wn * 32 + 16 + fr][fk]);
        acc[0][0] = __builtin_amdgcn_mfma_f32_16x16x32_f16(a0, b0, acc[0][0], 0, 0, 0);
        acc[0][1] = __builtin_amdgcn_mfma_f32_16x16x32_f16(a0, b1, acc[0][1], 0, 0, 0);
        acc[1][0] = __builtin_amdgcn_mfma_f32_16x16x32_f16(a1, b0, acc[1][0], 0, 0, 0);
        acc[1][1] = __builtin_amdgcn_mfma_f32_16x16x32_f16(a1, b1, acc[1][1], 0, 0, 0);
        __syncthreads();
    }
    int rbase = (lane >> 4) * 4;
#pragma unroll
    for (int mi = 0; mi < 2; mi++) {
#pragma unroll
        for (int r = 0; r < 4; r++) {
            int row = m0 + wm * 32 + mi * 16 + rbase + r;
            if (row < Ne) {
#pragma unroll
                for (int ni = 0; ni < 2; ni++) {
                    float v = gelu_tanh(acc[mi][ni][r]);
                    hh[(size_t)(base + row) * INTERM + n0 + wn * 32 + ni * 16 + fr] = (_Float16)v;
                }
            }
        }
    }
}

// ---------------- GEMM2: out[token] += w * (h @ W2[e]) ----------------
__global__ __launch_bounds__(256) void gemm2_kernel(const _Float16* __restrict__ hh,
                                                    const _Float16* __restrict__ w2t,
                                                    const int* __restrict__ cnt, const int* __restrict__ offs,
                                                    const int* __restrict__ row_tok, const float* __restrict__ row_w,
                                                    float* __restrict__ out) {
    int e = blockIdx.z;
    int Ne = cnt[e];
    int m0 = blockIdx.y * 64;
    if (m0 >= Ne) return;
    int base = offs[e];
    int n0 = blockIdx.x * 64;
    __shared__ __align__(16) _Float16 As[64][40];
    __shared__ __align__(16) _Float16 Bs[64][40];
    int tid = threadIdx.x;
    int lane = tid & 63;
    int w = tid >> 6, wm = w >> 1, wn = w & 1;
    int sr = tid >> 2, sc = (tid & 3) * 8;
    int arow = m0 + sr; if (arow >= Ne) arow = Ne - 1;
    const _Float16* aSrc = hh + (size_t)(base + arow) * INTERM + sc;
    const _Float16* bSrc = w2t + ((size_t)e * HID + (n0 + sr)) * INTERM + sc;
    f32x4 acc[2][2] = {};
    int fr = lane & 15;
    int fk = (lane >> 4) * 8;
    for (int k0 = 0; k0 < INTERM; k0 += 32) {
        *reinterpret_cast<f16x8*>(&As[sr][sc]) = *reinterpret_cast<const f16x8*>(aSrc + k0);
        *reinterpret_cast<f16x8*>(&Bs[sr][sc]) = *reinterpret_cast<const f16x8*>(bSrc + k0);
        __syncthreads();
        f16x8 a0 = *reinterpret_cast<const f16x8*>(&As[wm * 32 + fr][fk]);
        f16x8 a1 = *reinterpret_cast<const f16x8*>(&As[wm * 32 + 16 + fr][fk]);
        f16x8 b0 = *reinterpret_cast<const f16x8*>(&Bs[wn * 32 + fr][fk]);
        f16x8 b1 = *reinterpret_cast<const f16x8*>(&Bs[wn * 32 + 16 + fr][fk]);
        acc[0][0] = __builtin_amdgcn_mfma_f32_16x16x32_f16(a0, b0, acc[0][0], 0, 0, 0);
        acc[0][1] = __builtin_amdgcn_mfma_f32_16x16x32_f16(a0, b1, acc[0][1], 0, 0, 0);
        acc[1][0] = __builtin_amdgcn_mfma_f32_16x16x32_f16(a1, b0, acc[1][0], 0, 0, 0);
        acc[1][1] = __builtin_amdgcn_mfma_f32_16x16x32_f16(a1, b1, acc[1][1], 0, 0, 0);
        __syncthreads();
    }
    int rbase = (lane >> 4) * 4;
#pragma unroll
    for (int mi = 0; mi < 2; mi++) {
#pragma unroll
        for (int r = 0; r < 4; r++) {
            int row = m0 + wm * 32 + mi * 16 + rbase + r;
            if (row < Ne) {
                int tok = row_tok[base + row];
                float wgt = row_w[base + row];
#pragma unroll
                for (int ni = 0; ni < 2; ni++) {
                    atomicAdd(&out[(size_t)tok * HID + n0 + wn * 32 + ni * 16 + fr],
                              wgt * acc[mi][ni][r]);
                }
            }
        }
    }
}

extern "C" void kernel_launch(void* const* d_in, const int* in_sizes, int n_in,
                              void* d_out, int out_size, void* d_ws, size_t ws_size,
                              hipStream_t stream) {
    const float* x  = (const float*)d_in[0];
    const float* gw = (const float*)d_in[1];
    const float* w1 = (const float*)d_in[2];
    const float* w2 = (const float*)d_in[3];
    float* out = (float*)d_out;
    char* ws = (char*)d_ws;

    int*    cnt       = (int*)(ws + 0);
    int*    cursor    = (int*)(ws + 64);
    int*    offs      = (int*)(ws + 128);
    int*    part_cnt  = (int*)(ws + 1024);           // 8*256*4 = 8KB
    double* part_sumP = (double*)(ws + 16384);       // 8*256*8 = 16KB
    int*    row_tok   = (int*)(ws + 32768);          // 64KB
    float*  row_w     = (float*)(ws + 98304);        // 64KB
    int*    tk_idx    = (int*)(ws + 163840);         // 64KB
    float*  tk_w      = (float*)(ws + 229376);       // 64KB
    _Float16* xh  = (_Float16*)(ws + 294912);
    _Float16* w1t = (_Float16*)(ws + 294912 + 1ull * 33554432);
    _Float16* w2t = (_Float16*)(ws + 294912 + 2ull * 33554432);
    _Float16* hh  = (_Float16*)(ws + 294912 + 3ull * 33554432);

    hipMemsetAsync(d_out, 0, (size_t)out_size * sizeof(float), stream);

    cvt_kernel<<<2048, 256, 0, stream>>>(x, xh, T_TOKENS * HID / 4);
    dim3 g1(INTERM / 32, HID / 32, NEXP);
    tconv_kernel<<<g1, 256, 0, stream>>>(w1, w1t, HID, INTERM);   // w1t[e][i][h]
    dim3 g2(HID / 32, INTERM / 32, NEXP);
    tconv_kernel<<<g2, 256, 0, stream>>>(w2, w2t, INTERM, HID);   // w2t[e][h][i]

    gate_kernel<<<GATE_BLOCKS, 256, 0, stream>>>(x, gw, tk_idx, tk_w, part_cnt, part_sumP);
    finalize_kernel<<<1, 256, 0, stream>>>(part_cnt, part_sumP, cnt, offs, cursor,
                                           out + (size_t)T_TOKENS * HID);
    scatter_kernel<<<T_TOKENS / 256, 256, 0, stream>>>(tk_idx, tk_w, offs, cursor, row_tok, row_w);

    dim3 gg1(INTERM / 64, 128, NEXP);
    gemm1_kernel<<<gg1, 256, 0, stream>>>(xh, w1t, cnt, offs, row_tok, hh);
    dim3 gg2(HID / 64, 128, NEXP);
    gemm2_kernel<<<gg2, 256, 0, stream>>>(hh, w2t, cnt, offs, row_tok, row_w, out);
}

// Round 3
// 494.205 us; speedup vs baseline: 3.2138x; 1.4426x over previous
//
#include <hip/hip_runtime.h>
#include <hip/hip_fp16.h>
#include <cmath>

#define T_TOKENS 8192
#define HID 2048
#define NEXP 8
#define INTERM 1024
#define GATE_NB 2048

typedef _Float16 f16x8 __attribute__((ext_vector_type(8)));
typedef _Float16 f16x4 __attribute__((ext_vector_type(4)));
typedef float f32x4 __attribute__((ext_vector_type(4)));

static __device__ __forceinline__ float gelu_tanh(float v) {
    return 0.5f * v * (1.0f + tanhf(0.79788456080286535588f * (v + 0.044715f * v * v * v)));
}

static __device__ __forceinline__ void glds16(const void* g, void* l) {
    __builtin_amdgcn_global_load_lds((const __attribute__((address_space(1))) void*)g,
                                     (__attribute__((address_space(3))) void*)l, 16, 0, 0);
}

// ---------------- fp32 -> fp16 elementwise convert ----------------
__global__ void cvt_kernel(const float* __restrict__ in, _Float16* __restrict__ out, int n4) {
    int i = blockIdx.x * blockDim.x + threadIdx.x;
    int stride = gridDim.x * blockDim.x;
    for (; i < n4; i += stride) {
        float4 v = reinterpret_cast<const float4*>(in)[i];
        f16x4 o;
        o[0] = (_Float16)v.x; o[1] = (_Float16)v.y; o[2] = (_Float16)v.z; o[3] = (_Float16)v.w;
        reinterpret_cast<f16x4*>(out)[i] = o;
    }
}

// ------------- fp32 [Z][R][C] -> fp16 [Z][C][R] transpose-convert -------------
__global__ __launch_bounds__(256) void tconv_kernel(const float* __restrict__ in,
                                                    _Float16* __restrict__ out,
                                                    int R, int C) {
    __shared__ float t[32][33];
    int z = blockIdx.z;
    int r0 = blockIdx.y * 32, c0 = blockIdx.x * 32;
    int tid = threadIdx.x;
    int r = tid >> 3, c4 = (tid & 7) * 4;
    const float4 v = *reinterpret_cast<const float4*>(&in[((size_t)z * R + (r0 + r)) * C + c0 + c4]);
    t[r][c4 + 0] = v.x; t[r][c4 + 1] = v.y; t[r][c4 + 2] = v.z; t[r][c4 + 3] = v.w;
    __syncthreads();
    int oc = tid >> 3;
    int or4 = (tid & 7) * 4;
    f16x4 o;
    o[0] = (_Float16)t[or4 + 0][oc];
    o[1] = (_Float16)t[or4 + 1][oc];
    o[2] = (_Float16)t[or4 + 2][oc];
    o[3] = (_Float16)t[or4 + 3][oc];
    *reinterpret_cast<f16x4*>(&out[((size_t)z * C + (c0 + oc)) * R + r0 + or4]) = o;
}

// ---------------- gating: one wave per token, streaming accumulate ----------------
__global__ __launch_bounds__(256) void gate_kernel(const float* __restrict__ x,
                                                   const float* __restrict__ gw,
                                                   int* __restrict__ tk_idx, float* __restrict__ tk_w,
                                                   int* __restrict__ part_cnt,      // [NEXP][GATE_NB]
                                                   double* __restrict__ part_sumP)  // [NEXP][GATE_NB]
{
    __shared__ double sds[4][NEXP];
    __shared__ int sci[4][NEXP];
    int w = threadIdx.x >> 6;
    int lane = threadIdx.x & 63;
    int t = blockIdx.x * 4 + w;           // GATE_NB*4 == T_TOKENS exactly

    const float4* xr = (const float4*)(x + (size_t)t * HID);
    double acc[NEXP];
#pragma unroll
    for (int e = 0; e < NEXP; e++) acc[e] = 0.0;
#pragma unroll
    for (int i = 0; i < HID / 256; i++) {      // 8 iters, 64 lanes x float4
        float4 xv = xr[i * 64 + lane];
#pragma unroll
        for (int e = 0; e < NEXP; e++) {
            float4 gv = ((const float4*)(gw + (size_t)e * HID))[i * 64 + lane];
            acc[e] += (double)xv.x * (double)gv.x + (double)xv.y * (double)gv.y
                    + (double)xv.z * (double)gv.z + (double)xv.w * (double)gv.w;
        }
    }
#pragma unroll
    for (int e = 0; e < NEXP; e++) {
#pragma unroll
        for (int off = 32; off > 0; off >>= 1) acc[e] += __shfl_xor(acc[e], off, 64);
    }
    // softmax + top-2 redundantly on all lanes (values wave-uniform)
    double mx = acc[0];
#pragma unroll
    for (int e = 1; e < NEXP; e++) mx = acc[e] > mx ? acc[e] : mx;
    double ex[NEXP];
    double sum = 0.0;
#pragma unroll
    for (int e = 0; e < NEXP; e++) { ex[e] = exp(acc[e] - mx); sum += ex[e]; }
    int i0 = 0;
#pragma unroll
    for (int e = 1; e < NEXP; e++) if (ex[e] > ex[i0]) i0 = e;
    int i1 = (i0 == 0) ? 1 : 0;
#pragma unroll
    for (int e = 0; e < NEXP; e++) if (e != i0 && ex[e] > ex[i1]) i1 = e;
    double p0 = ex[i0], p1 = ex[i1];
    double t2 = p0 + p1;
    if (lane == 0) {
        tk_idx[2 * t] = i0; tk_idx[2 * t + 1] = i1;
        tk_w[2 * t] = (float)(p0 / t2); tk_w[2 * t + 1] = (float)(p1 / t2);
#pragma unroll
        for (int e = 0; e < NEXP; e++) {
            sds[w][e] = ex[e] / sum;
            sci[w][e] = (e == i0 ? 1 : 0) + (e == i1 ? 1 : 0);
        }
    }
    __syncthreads();
    if (threadIdx.x < NEXP) {
        int e = threadIdx.x;
        part_sumP[e * GATE_NB + blockIdx.x] = sds[0][e] + sds[1][e] + sds[2][e] + sds[3][e];
        part_cnt[e * GATE_NB + blockIdx.x]  = sci[0][e] + sci[1][e] + sci[2][e] + sci[3][e];
    }
}

// ---------------- reduce partials, offsets scan, aux loss, zero cursor ----------------
__global__ __launch_bounds__(256) void finalize_kernel(const int* __restrict__ part_cnt,
                                                       const double* __restrict__ part_sumP,
                                                       int* __restrict__ cnt, int* __restrict__ offs,
                                                       int* __restrict__ cursor,
                                                       float* __restrict__ aux_out) {
    __shared__ double swv[4];
    __shared__ int cwv[4];
    __shared__ double sE[NEXP];
    __shared__ int cE[NEXP];
    int w = threadIdx.x >> 6;
    int lane = threadIdx.x & 63;
    for (int e = 0; e < NEXP; e++) {
        double s = 0.0; int c = 0;
        for (int j = threadIdx.x; j < GATE_NB; j += 256) {
            s += part_sumP[e * GATE_NB + j];
            c += part_cnt[e * GATE_NB + j];
        }
#pragma unroll
        for (int off = 32; off > 0; off >>= 1) {
            s += __shfl_xor(s, off, 64);
            c += __shfl_xor(c, off, 64);
        }
        if (lane == 0) { swv[w] = s; cwv[w] = c; }
        __syncthreads();
        if (threadIdx.x == 0) {
            sE[e] = swv[0] + swv[1] + swv[2] + swv[3];
            cE[e] = cwv[0] + cwv[1] + cwv[2] + cwv[3];
        }
        __syncthreads();
    }
    if (threadIdx.x == 0) {
        int off = 0;
        double aux = 0.0;
#pragma unroll
        for (int e = 0; e < NEXP; e++) {
            cnt[e] = cE[e];
            offs[e] = off;
            off += cE[e];
            cursor[e] = 0;
            aux += ((double)cE[e] / (double)T_TOKENS) * (sE[e] / (double)T_TOKENS);
        }
        aux_out[0] = (float)(0.01 * (double)NEXP * aux);
    }
}

// ---------------- build per-expert row lists (wave-aggregated atomics) ----------------
__global__ void scatter_kernel(const int* __restrict__ tk_idx, const float* __restrict__ tk_w,
                               const int* __restrict__ offs, int* __restrict__ cursor,
                               int* __restrict__ row_tok, float* __restrict__ row_w) {
    int t = blockIdx.x * blockDim.x + threadIdx.x;
    int lane = threadIdx.x & 63;
    unsigned long long below = (lane == 0) ? 0ull : ((~0ull) >> (64 - lane));
    for (int k = 0; k < 2; k++) {
        int e = tk_idx[2 * t + k];
        float wv = tk_w[2 * t + k];
        int pos = 0;
#pragma unroll
        for (int ee = 0; ee < NEXP; ee++) {
            unsigned long long m = __ballot(e == ee);
            if (e == ee) {
                int rank = (int)__popcll(m & below);
                int leader = (int)__ffsll((unsigned long long)m) - 1;
                int base = 0;
                if (lane == leader) base = atomicAdd(&cursor[ee], (int)__popcll(m));
                base = __shfl(base, leader, 64);
                pos = base + rank;
            }
        }
        int r = offs[e] + pos;
        row_tok[r] = t;
        row_w[r] = wv;
    }
}

// ---------------- GEMM1: h = gelu(Xe @ W1[e]), 128x128 tile, glds staging ----------------
__global__ __launch_bounds__(256) void gemm1_kernel(const _Float16* __restrict__ xh,
                                                    const _Float16* __restrict__ w1t,
                                                    const int* __restrict__ cnt, const int* __restrict__ offs,
                                                    const int* __restrict__ row_tok,
                                                    _Float16* __restrict__ hh) {
    int e = blockIdx.z;
    int Ne = cnt[e];
    int m0 = blockIdx.y * 128;
    if (m0 >= Ne) return;
    int base = offs[e];
    int n0 = blockIdx.x * 128;

    __shared__ __align__(16) _Float16 As[128][32];
    __shared__ __align__(16) _Float16 Bs[128][32];

    int tid = threadIdx.x;
    int lane = tid & 63;
    int w = tid >> 6, wm = w >> 1, wn = w & 1;

    // staging: wave w stages rows [32w, 32w+32) of As and Bs; per 1KB issue:
    // lane covers row j*16 + (lane>>2), k-halfword (lane&3)*8 elements
    int r0 = lane >> 2;
    int kh = (lane & 3) * 8;
    int rowA0 = m0 + w * 32 + r0;      if (rowA0 >= Ne) rowA0 = Ne - 1;
    int rowA1 = m0 + w * 32 + 16 + r0; if (rowA1 >= Ne) rowA1 = Ne - 1;
    int tok0 = row_tok[base + rowA0];
    int tok1 = row_tok[base + rowA1];
    const _Float16* aSrc0 = xh + (size_t)tok0 * HID + kh;
    const _Float16* aSrc1 = xh + (size_t)tok1 * HID + kh;
    const _Float16* bSrc0 = w1t + ((size_t)e * INTERM + n0 + w * 32 + r0) * HID + kh;
    const _Float16* bSrc1 = w1t + ((size_t)e * INTERM + n0 + w * 32 + 16 + r0) * HID + kh;
    _Float16* ldsA0 = &As[w * 32][0];
    _Float16* ldsA1 = &As[w * 32 + 16][0];
    _Float16* ldsB0 = &Bs[w * 32][0];
    _Float16* ldsB1 = &Bs[w * 32 + 16][0];

    f32x4 acc[4][4] = {};
    int fr = lane & 15;
    int fq = lane >> 4;
    int fk = fq * 8;

    for (int k0 = 0; k0 < HID; k0 += 32) {
        glds16(aSrc0 + k0, ldsA0);
        glds16(aSrc1 + k0, ldsA1);
        glds16(bSrc0 + k0, ldsB0);
        glds16(bSrc1 + k0, ldsB1);
        __syncthreads();
        f16x8 a[4], b[4];
#pragma unroll
        for (int mi = 0; mi < 4; mi++) a[mi] = *(const f16x8*)&As[wm * 64 + mi * 16 + fr][fk];
#pragma unroll
        for (int ni = 0; ni < 4; ni++) b[ni] = *(const f16x8*)&Bs[wn * 64 + ni * 16 + fr][fk];
#pragma unroll
        for (int mi = 0; mi < 4; mi++)
#pragma unroll
            for (int ni = 0; ni < 4; ni++)
                acc[mi][ni] = __builtin_amdgcn_mfma_f32_16x16x32_f16(a[mi], b[ni], acc[mi][ni], 0, 0, 0);
        __syncthreads();
    }

#pragma unroll
    for (int mi = 0; mi < 4; mi++) {
#pragma unroll
        for (int r = 0; r < 4; r++) {
            int row = m0 + wm * 64 + mi * 16 + fq * 4 + r;
            if (row < Ne) {
                _Float16* dst = hh + (size_t)(base + row) * INTERM + n0 + wn * 64 + fr;
#pragma unroll
                for (int ni = 0; ni < 4; ni++)
                    dst[ni * 16] = (_Float16)gelu_tanh(acc[mi][ni][r]);
            }
        }
    }
}

// ---------------- GEMM2: out[token] += w * (h @ W2[e]), 128x128 tile ----------------
__global__ __launch_bounds__(256) void gemm2_kernel(const _Float16* __restrict__ hh,
                                                    const _Float16* __restrict__ w2t,
                                                    const int* __restrict__ cnt, const int* __restrict__ offs,
                                                    const int* __restrict__ row_tok, const float* __restrict__ row_w,
                                                    float* __restrict__ out) {
    int e = blockIdx.z;
    int Ne = cnt[e];
    int m0 = blockIdx.y * 128;
    if (m0 >= Ne) return;
    int base = offs[e];
    int n0 = blockIdx.x * 128;

    __shared__ __align__(16) _Float16 As[128][32];
    __shared__ __align__(16) _Float16 Bs[128][32];

    int tid = threadIdx.x;
    int lane = tid & 63;
    int w = tid >> 6, wm = w >> 1, wn = w & 1;

    int r0 = lane >> 2;
    int kh = (lane & 3) * 8;
    int rowA0 = m0 + w * 32 + r0;      if (rowA0 >= Ne) rowA0 = Ne - 1;
    int rowA1 = m0 + w * 32 + 16 + r0; if (rowA1 >= Ne) rowA1 = Ne - 1;
    const _Float16* aSrc0 = hh + (size_t)(base + rowA0) * INTERM + kh;
    const _Float16* aSrc1 = hh + (size_t)(base + rowA1) * INTERM + kh;
    const _Float16* bSrc0 = w2t + ((size_t)e * HID + n0 + w * 32 + r0) * INTERM + kh;
    const _Float16* bSrc1 = w2t + ((size_t)e * HID + n0 + w * 32 + 16 + r0) * INTERM + kh;
    _Float16* ldsA0 = &As[w * 32][0];
    _Float16* ldsA1 = &As[w * 32 + 16][0];
    _Float16* ldsB0 = &Bs[w * 32][0];
    _Float16* ldsB1 = &Bs[w * 32 + 16][0];

    f32x4 acc[4][4] = {};
    int fr = lane & 15;
    int fq = lane >> 4;
    int fk = fq * 8;

    for (int k0 = 0; k0 < INTERM; k0 += 32) {
        glds16(aSrc0 + k0, ldsA0);
        glds16(aSrc1 + k0, ldsA1);
        glds16(bSrc0 + k0, ldsB0);
        glds16(bSrc1 + k0, ldsB1);
        __syncthreads();
        f16x8 a[4], b[4];
#pragma unroll
        for (int mi = 0; mi < 4; mi++) a[mi] = *(const f16x8*)&As[wm * 64 + mi * 16 + fr][fk];
#pragma unroll
        for (int ni = 0; ni < 4; ni++) b[ni] = *(const f16x8*)&Bs[wn * 64 + ni * 16 + fr][fk];
#pragma unroll
        for (int mi = 0; mi < 4; mi++)
#pragma unroll
            for (int ni = 0; ni < 4; ni++)
                acc[mi][ni] = __builtin_amdgcn_mfma_f32_16x16x32_f16(a[mi], b[ni], acc[mi][ni], 0, 0, 0);
        __syncthreads();
    }

#pragma unroll
    for (int mi = 0; mi < 4; mi++) {
#pragma unroll
        for (int r = 0; r < 4; r++) {
            int row = m0 + wm * 64 + mi * 16 + fq * 4 + r;
            if (row < Ne) {
                int tok = row_tok[base + row];
                float wgt = row_w[base + row];
                float* dst = out + (size_t)tok * HID + n0 + wn * 64 + fr;
#pragma unroll
                for (int ni = 0; ni < 4; ni++)
                    atomicAdd(&dst[ni * 16], wgt * acc[mi][ni][r]);
            }
        }
    }
}

extern "C" void kernel_launch(void* const* d_in, const int* in_sizes, int n_in,
                              void* d_out, int out_size, void* d_ws, size_t ws_size,
                              hipStream_t stream) {
    const float* x  = (const float*)d_in[0];
    const float* gw = (const float*)d_in[1];
    const float* w1 = (const float*)d_in[2];
    const float* w2 = (const float*)d_in[3];
    float* out = (float*)d_out;
    char* ws = (char*)d_ws;

    int*    cnt       = (int*)(ws + 0);
    int*    cursor    = (int*)(ws + 64);
    int*    offs      = (int*)(ws + 128);
    int*    part_cnt  = (int*)(ws + 4096);           // 8*2048*4 = 64KB
    double* part_sumP = (double*)(ws + 131072);      // 8*2048*8 = 128KB
    int*    row_tok   = (int*)(ws + 262144);         // 64KB
    float*  row_w     = (float*)(ws + 327680);       // 64KB
    int*    tk_idx    = (int*)(ws + 393216);         // 64KB
    float*  tk_w      = (float*)(ws + 458752);       // 64KB
    _Float16* xh  = (_Float16*)(ws + 524288);                      // 32MB
    _Float16* w1t = (_Float16*)(ws + 524288 + 1ull * 33554432);    // 32MB
    _Float16* w2t = (_Float16*)(ws + 524288 + 2ull * 33554432);    // 32MB
    _Float16* hh  = (_Float16*)(ws + 524288 + 3ull * 33554432);    // 32MB

    hipMemsetAsync(d_out, 0, (size_t)out_size * sizeof(float), stream);

    cvt_kernel<<<2048, 256, 0, stream>>>(x, xh, T_TOKENS * HID / 4);
    dim3 g1(INTERM / 32, HID / 32, NEXP);
    tconv_kernel<<<g1, 256, 0, stream>>>(w1, w1t, HID, INTERM);   // w1t[e][i][h]
    dim3 g2(HID / 32, INTERM / 32, NEXP);
    tconv_kernel<<<g2, 256, 0, stream>>>(w2, w2t, INTERM, HID);   // w2t[e][h][i]

    gate_kernel<<<GATE_NB, 256, 0, stream>>>(x, gw, tk_idx, tk_w, part_cnt, part_sumP);
    finalize_kernel<<<1, 256, 0, stream>>>(part_cnt, part_sumP, cnt, offs, cursor,
                                           out + (size_t)T_TOKENS * HID);
    scatter_kernel<<<T_TOKENS / 256, 256, 0, stream>>>(tk_idx, tk_w, offs, cursor, row_tok, row_w);

    dim3 gg1(INTERM / 128, 64, NEXP);
    gemm1_kernel<<<gg1, 256, 0, stream>>>(xh, w1t, cnt, offs, row_tok, hh);
    dim3 gg2(HID / 128, 64, NEXP);
    gemm2_kernel<<<gg2, 256, 0, stream>>>(hh, w2t, cnt, offs, row_tok, row_w, out);
}

// Round 4
// 409.443 us; speedup vs baseline: 3.8791x; 1.2070x over previous
//
#include <hip/hip_runtime.h>
#include <hip/hip_fp16.h>
#include <cmath>

#define T_TOKENS 8192
#define HID 2048
#define NEXP 8
#define INTERM 1024
#define GATE_NB 2048

typedef _Float16 f16x8 __attribute__((ext_vector_type(8)));
typedef _Float16 f16x4 __attribute__((ext_vector_type(4)));
typedef float f32x4 __attribute__((ext_vector_type(4)));

static __device__ __forceinline__ float gelu_tanh(float v) {
    return 0.5f * v * (1.0f + tanhf(0.79788456080286535588f * (v + 0.044715f * v * v * v)));
}

static __device__ __forceinline__ void glds16(const void* g, void* l) {
    __builtin_amdgcn_global_load_lds((const __attribute__((address_space(1))) void*)g,
                                     (__attribute__((address_space(3))) void*)l, 16, 0, 0);
}

// ------------- fp32 [Z][R][C] -> fp16 [Z][C][R] transpose-convert -------------
__global__ __launch_bounds__(256) void tconv_kernel(const float* __restrict__ in,
                                                    _Float16* __restrict__ out,
                                                    int R, int C) {
    __shared__ float t[32][33];
    int z = blockIdx.z;
    int r0 = blockIdx.y * 32, c0 = blockIdx.x * 32;
    int tid = threadIdx.x;
    int r = tid >> 3, c4 = (tid & 7) * 4;
    const float4 v = *reinterpret_cast<const float4*>(&in[((size_t)z * R + (r0 + r)) * C + c0 + c4]);
    t[r][c4 + 0] = v.x; t[r][c4 + 1] = v.y; t[r][c4 + 2] = v.z; t[r][c4 + 3] = v.w;
    __syncthreads();
    int oc = tid >> 3;
    int or4 = (tid & 7) * 4;
    f16x4 o;
    o[0] = (_Float16)t[or4 + 0][oc];
    o[1] = (_Float16)t[or4 + 1][oc];
    o[2] = (_Float16)t[or4 + 2][oc];
    o[3] = (_Float16)t[or4 + 3][oc];
    *reinterpret_cast<f16x4*>(&out[((size_t)z * C + (c0 + oc)) * R + r0 + or4]) = o;
}

// -------- gating: one wave per token; also emits xh = fp16(x) on the fly --------
__global__ __launch_bounds__(256) void gate_kernel(const float* __restrict__ x,
                                                   const float* __restrict__ gw,
                                                   _Float16* __restrict__ xh,
                                                   int* __restrict__ tk_idx, float* __restrict__ tk_w,
                                                   int* __restrict__ part_cnt,      // [NEXP][GATE_NB]
                                                   double* __restrict__ part_sumP)  // [NEXP][GATE_NB]
{
    __shared__ double sds[4][NEXP];
    __shared__ int sci[4][NEXP];
    int w = threadIdx.x >> 6;
    int lane = threadIdx.x & 63;
    int t = blockIdx.x * 4 + w;           // GATE_NB*4 == T_TOKENS exactly

    const float4* xr = (const float4*)(x + (size_t)t * HID);
    _Float16* xo = xh + (size_t)t * HID;
    double acc[NEXP];
#pragma unroll
    for (int e = 0; e < NEXP; e++) acc[e] = 0.0;
#pragma unroll
    for (int i = 0; i < HID / 256; i++) {      // 8 iters, 64 lanes x float4
        float4 xv = xr[i * 64 + lane];
        f16x4 h;
        h[0] = (_Float16)xv.x; h[1] = (_Float16)xv.y;
        h[2] = (_Float16)xv.z; h[3] = (_Float16)xv.w;
        *reinterpret_cast<f16x4*>(xo + i * 256 + lane * 4) = h;
#pragma unroll
        for (int e = 0; e < NEXP; e++) {
            float4 gv = ((const float4*)(gw + (size_t)e * HID))[i * 64 + lane];
            acc[e] += (double)xv.x * (double)gv.x + (double)xv.y * (double)gv.y
                    + (double)xv.z * (double)gv.z + (double)xv.w * (double)gv.w;
        }
    }
#pragma unroll
    for (int e = 0; e < NEXP; e++) {
#pragma unroll
        for (int off = 32; off > 0; off >>= 1) acc[e] += __shfl_xor(acc[e], off, 64);
    }
    double mx = acc[0];
#pragma unroll
    for (int e = 1; e < NEXP; e++) mx = acc[e] > mx ? acc[e] : mx;
    double ex[NEXP];
    double sum = 0.0;
#pragma unroll
    for (int e = 0; e < NEXP; e++) { ex[e] = exp(acc[e] - mx); sum += ex[e]; }
    int i0 = 0;
#pragma unroll
    for (int e = 1; e < NEXP; e++) if (ex[e] > ex[i0]) i0 = e;
    int i1 = (i0 == 0) ? 1 : 0;
#pragma unroll
    for (int e = 0; e < NEXP; e++) if (e != i0 && ex[e] > ex[i1]) i1 = e;
    double p0 = ex[i0], p1 = ex[i1];
    double t2 = p0 + p1;
    if (lane == 0) {
        tk_idx[2 * t] = i0; tk_idx[2 * t + 1] = i1;
        tk_w[2 * t] = (float)(p0 / t2); tk_w[2 * t + 1] = (float)(p1 / t2);
#pragma unroll
        for (int e = 0; e < NEXP; e++) {
            sds[w][e] = ex[e] / sum;
            sci[w][e] = (e == i0 ? 1 : 0) + (e == i1 ? 1 : 0);
        }
    }
    __syncthreads();
    if (threadIdx.x < NEXP) {
        int e = threadIdx.x;
        part_sumP[e * GATE_NB + blockIdx.x] = sds[0][e] + sds[1][e] + sds[2][e] + sds[3][e];
        part_cnt[e * GATE_NB + blockIdx.x]  = sci[0][e] + sci[1][e] + sci[2][e] + sci[3][e];
    }
}

// ---------------- reduce partials, offsets scan, aux loss, zero cursor ----------------
__global__ __launch_bounds__(256) void finalize_kernel(const int* __restrict__ part_cnt,
                                                       const double* __restrict__ part_sumP,
                                                       int* __restrict__ cnt, int* __restrict__ offs,
                                                       int* __restrict__ cursor,
                                                       float* __restrict__ aux_out) {
    __shared__ double swv[4];
    __shared__ int cwv[4];
    __shared__ double sE[NEXP];
    __shared__ int cE[NEXP];
    int w = threadIdx.x >> 6;
    int lane = threadIdx.x & 63;
    for (int e = 0; e < NEXP; e++) {
        double s = 0.0; int c = 0;
        for (int j = threadIdx.x; j < GATE_NB; j += 256) {
            s += part_sumP[e * GATE_NB + j];
            c += part_cnt[e * GATE_NB + j];
        }
#pragma unroll
        for (int off = 32; off > 0; off >>= 1) {
            s += __shfl_xor(s, off, 64);
            c += __shfl_xor(c, off, 64);
        }
        if (lane == 0) { swv[w] = s; cwv[w] = c; }
        __syncthreads();
        if (threadIdx.x == 0) {
            sE[e] = swv[0] + swv[1] + swv[2] + swv[3];
            cE[e] = cwv[0] + cwv[1] + cwv[2] + cwv[3];
        }
        __syncthreads();
    }
    if (threadIdx.x == 0) {
        int off = 0;
        double aux = 0.0;
#pragma unroll
        for (int e = 0; e < NEXP; e++) {
            cnt[e] = cE[e];
            offs[e] = off;
            off += cE[e];
            cursor[e] = 0;
            aux += ((double)cE[e] / (double)T_TOKENS) * (sE[e] / (double)T_TOKENS);
        }
        aux_out[0] = (float)(0.01 * (double)NEXP * aux);
    }
}

// ------- build per-expert row lists + inverse map (wave-aggregated atomics) -------
__global__ void scatter_kernel(const int* __restrict__ tk_idx, const float* __restrict__ tk_w,
                               const int* __restrict__ offs, int* __restrict__ cursor,
                               int* __restrict__ row_tok, float* __restrict__ row_w,
                               int* __restrict__ tok_row) {
    int t = blockIdx.x * blockDim.x + threadIdx.x;
    int lane = threadIdx.x & 63;
    unsigned long long below = (lane == 0) ? 0ull : ((~0ull) >> (64 - lane));
    for (int k = 0; k < 2; k++) {
        int e = tk_idx[2 * t + k];
        float wv = tk_w[2 * t + k];
        int pos = 0;
#pragma unroll
        for (int ee = 0; ee < NEXP; ee++) {
            unsigned long long m = __ballot(e == ee);
            if (e == ee) {
                int rank = (int)__popcll(m & below);
                int leader = (int)__ffsll((unsigned long long)m) - 1;
                int base = 0;
                if (lane == leader) base = atomicAdd(&cursor[ee], (int)__popcll(m));
                base = __shfl(base, leader, 64);
                pos = base + rank;
            }
        }
        int r = offs[e] + pos;
        row_tok[r] = t;
        row_w[r] = wv;
        tok_row[2 * t + k] = r;
    }
}

// ---------------- GEMM1: h = gelu(Xe @ W1[e]), 128x128, glds + XOR-swizzled LDS ----------------
__global__ __launch_bounds__(256) void gemm1_kernel(const _Float16* __restrict__ xh,
                                                    const _Float16* __restrict__ w1t,
                                                    const int* __restrict__ cnt, const int* __restrict__ offs,
                                                    const int* __restrict__ row_tok,
                                                    _Float16* __restrict__ hh) {
    int e = blockIdx.z;
    int Ne = cnt[e];
    int m0 = blockIdx.y * 128;
    if (m0 >= Ne) return;
    int base = offs[e];
    int n0 = blockIdx.x * 128;

    __shared__ __align__(16) _Float16 As[128][32];
    __shared__ __align__(16) _Float16 Bs[128][32];

    int tid = threadIdx.x;
    int lane = tid & 63;
    int w = tid >> 6, wm = w >> 1, wn = w & 1;

    // staging: lane -> row r0=lane>>2; global chunk is XOR-pre-swizzled so the
    // linear glds destination yields phys_chunk = chunk ^ ((row>>1)&3) in LDS.
    int r0 = lane >> 2;
    int kh = (((lane & 3) ^ ((lane >> 3) & 3))) * 8;
    int rowA0 = m0 + w * 32 + r0;      if (rowA0 >= Ne) rowA0 = Ne - 1;
    int rowA1 = m0 + w * 32 + 16 + r0; if (rowA1 >= Ne) rowA1 = Ne - 1;
    int tok0 = row_tok[base + rowA0];
    int tok1 = row_tok[base + rowA1];
    const _Float16* aSrc0 = xh + (size_t)tok0 * HID + kh;
    const _Float16* aSrc1 = xh + (size_t)tok1 * HID + kh;
    const _Float16* bSrc0 = w1t + ((size_t)e * INTERM + n0 + w * 32 + r0) * HID + kh;
    const _Float16* bSrc1 = w1t + ((size_t)e * INTERM + n0 + w * 32 + 16 + r0) * HID + kh;
    _Float16* ldsA0 = &As[w * 32][0];
    _Float16* ldsA1 = &As[w * 32 + 16][0];
    _Float16* ldsB0 = &Bs[w * 32][0];
    _Float16* ldsB1 = &Bs[w * 32 + 16][0];

    f32x4 acc[4][4] = {};
    int fr = lane & 15;
    int fq = lane >> 4;
    int fk = (fq ^ ((fr >> 1) & 3)) * 8;   // swizzled read chunk

    for (int k0 = 0; k0 < HID; k0 += 32) {
        glds16(aSrc0 + k0, ldsA0);
        glds16(aSrc1 + k0, ldsA1);
        glds16(bSrc0 + k0, ldsB0);
        glds16(bSrc1 + k0, ldsB1);
        __syncthreads();
        f16x8 a[4], b[4];
#pragma unroll
        for (int mi = 0; mi < 4; mi++) a[mi] = *(const f16x8*)&As[wm * 64 + mi * 16 + fr][fk];
#pragma unroll
        for (int ni = 0; ni < 4; ni++) b[ni] = *(const f16x8*)&Bs[wn * 64 + ni * 16 + fr][fk];
#pragma unroll
        for (int mi = 0; mi < 4; mi++)
#pragma unroll
            for (int ni = 0; ni < 4; ni++)
                acc[mi][ni] = __builtin_amdgcn_mfma_f32_16x16x32_f16(a[mi], b[ni], acc[mi][ni], 0, 0, 0);
        __syncthreads();
    }

    int fq4 = fq * 4;
#pragma unroll
    for (int mi = 0; mi < 4; mi++) {
#pragma unroll
        for (int r = 0; r < 4; r++) {
            int row = m0 + wm * 64 + mi * 16 + fq4 + r;
            if (row < Ne) {
                _Float16* dst = hh + (size_t)(base + row) * INTERM + n0 + wn * 64 + fr;
#pragma unroll
                for (int ni = 0; ni < 4; ni++)
                    dst[ni * 16] = (_Float16)gelu_tanh(acc[mi][ni][r]);
            }
        }
    }
}

// ---------------- GEMM2: y[r] = h[r] @ W2[e]  (plain fp16 stores, no atomics) ----------------
__global__ __launch_bounds__(256) void gemm2_kernel(const _Float16* __restrict__ hh,
                                                    const _Float16* __restrict__ w2t,
                                                    const int* __restrict__ cnt, const int* __restrict__ offs,
                                                    _Float16* __restrict__ y) {
    int e = blockIdx.z;
    int Ne = cnt[e];
    int m0 = blockIdx.y * 128;
    if (m0 >= Ne) return;
    int base = offs[e];
    int n0 = blockIdx.x * 128;

    __shared__ __align__(16) _Float16 As[128][32];
    __shared__ __align__(16) _Float16 Bs[128][32];

    int tid = threadIdx.x;
    int lane = tid & 63;
    int w = tid >> 6, wm = w >> 1, wn = w & 1;

    int r0 = lane >> 2;
    int kh = (((lane & 3) ^ ((lane >> 3) & 3))) * 8;
    int rowA0 = m0 + w * 32 + r0;      if (rowA0 >= Ne) rowA0 = Ne - 1;
    int rowA1 = m0 + w * 32 + 16 + r0; if (rowA1 >= Ne) rowA1 = Ne - 1;
    const _Float16* aSrc0 = hh + (size_t)(base + rowA0) * INTERM + kh;
    const _Float16* aSrc1 = hh + (size_t)(base + rowA1) * INTERM + kh;
    const _Float16* bSrc0 = w2t + ((size_t)e * HID + n0 + w * 32 + r0) * INTERM + kh;
    const _Float16* bSrc1 = w2t + ((size_t)e * HID + n0 + w * 32 + 16 + r0) * INTERM + kh;
    _Float16* ldsA0 = &As[w * 32][0];
    _Float16* ldsA1 = &As[w * 32 + 16][0];
    _Float16* ldsB0 = &Bs[w * 32][0];
    _Float16* ldsB1 = &Bs[w * 32 + 16][0];

    f32x4 acc[4][4] = {};
    int fr = lane & 15;
    int fq = lane >> 4;
    int fk = (fq ^ ((fr >> 1) & 3)) * 8;

    for (int k0 = 0; k0 < INTERM; k0 += 32) {
        glds16(aSrc0 + k0, ldsA0);
        glds16(aSrc1 + k0, ldsA1);
        glds16(bSrc0 + k0, ldsB0);
        glds16(bSrc1 + k0, ldsB1);
        __syncthreads();
        f16x8 a[4], b[4];
#pragma unroll
        for (int mi = 0; mi < 4; mi++) a[mi] = *(const f16x8*)&As[wm * 64 + mi * 16 + fr][fk];
#pragma unroll
        for (int ni = 0; ni < 4; ni++) b[ni] = *(const f16x8*)&Bs[wn * 64 + ni * 16 + fr][fk];
#pragma unroll
        for (int mi = 0; mi < 4; mi++)
#pragma unroll
            for (int ni = 0; ni < 4; ni++)
                acc[mi][ni] = __builtin_amdgcn_mfma_f32_16x16x32_f16(a[mi], b[ni], acc[mi][ni], 0, 0, 0);
        __syncthreads();
    }

    int fq4 = fq * 4;
#pragma unroll
    for (int mi = 0; mi < 4; mi++) {
#pragma unroll
        for (int r = 0; r < 4; r++) {
            int row = m0 + wm * 64 + mi * 16 + fq4 + r;
            if (row < Ne) {
                _Float16* dst = y + (size_t)(base + row) * HID + n0 + wn * 64 + fr;
#pragma unroll
                for (int ni = 0; ni < 4; ni++)
                    dst[ni * 16] = (_Float16)acc[mi][ni][r];
            }
        }
    }
}

// ---------------- combine: out[t] = w0*y[r0] + w1*y[r1] ----------------
__global__ __launch_bounds__(256) void combine_kernel(const _Float16* __restrict__ y,
                                                      const int* __restrict__ tok_row,
                                                      const float* __restrict__ tk_w,
                                                      float* __restrict__ out) {
    int t = blockIdx.x;
    int c = threadIdx.x;          // 256 threads x 8 elems = 2048
    int r0 = tok_row[2 * t], r1 = tok_row[2 * t + 1];
    float w0 = tk_w[2 * t], w1 = tk_w[2 * t + 1];
    f16x8 a = reinterpret_cast<const f16x8*>(y + (size_t)r0 * HID)[c];
    f16x8 b = reinterpret_cast<const f16x8*>(y + (size_t)r1 * HID)[c];
    float4 o0, o1;
    o0.x = w0 * (float)a[0] + w1 * (float)b[0];
    o0.y = w0 * (float)a[1] + w1 * (float)b[1];
    o0.z = w0 * (float)a[2] + w1 * (float)b[2];
    o0.w = w0 * (float)a[3] + w1 * (float)b[3];
    o1.x = w0 * (float)a[4] + w1 * (float)b[4];
    o1.y = w0 * (float)a[5] + w1 * (float)b[5];
    o1.z = w0 * (float)a[6] + w1 * (float)b[6];
    o1.w = w0 * (float)a[7] + w1 * (float)b[7];
    float4* dst = reinterpret_cast<float4*>(out + (size_t)t * HID + c * 8);
    dst[0] = o0;
    dst[1] = o1;
}

extern "C" void kernel_launch(void* const* d_in, const int* in_sizes, int n_in,
                              void* d_out, int out_size, void* d_ws, size_t ws_size,
                              hipStream_t stream) {
    const float* x  = (const float*)d_in[0];
    const float* gw = (const float*)d_in[1];
    const float* w1 = (const float*)d_in[2];
    const float* w2 = (const float*)d_in[3];
    float* out = (float*)d_out;
    char* ws = (char*)d_ws;

    int*    cnt       = (int*)(ws + 0);
    int*    cursor    = (int*)(ws + 64);
    int*    offs      = (int*)(ws + 128);
    int*    part_cnt  = (int*)(ws + 4096);           // 8*2048*4 = 64KB
    double* part_sumP = (double*)(ws + 131072);      // 8*2048*8 = 128KB
    int*    row_tok   = (int*)(ws + 262144);         // 64KB
    float*  row_w     = (float*)(ws + 327680);       // 64KB
    int*    tk_idx    = (int*)(ws + 393216);         // 64KB
    float*  tk_w      = (float*)(ws + 458752);       // 64KB
    int*    tok_row   = (int*)(ws + 524288);         // 64KB
    const size_t OFF = 589824;
    _Float16* xh  = (_Float16*)(ws + OFF);                      // 32MB
    _Float16* w1t = (_Float16*)(ws + OFF + (1ull << 25));       // 32MB
    _Float16* w2t = (_Float16*)(ws + OFF + (2ull << 25));       // 32MB
    _Float16* hh  = (_Float16*)(ws + OFF + (3ull << 25));       // 32MB
    _Float16* y   = (_Float16*)(ws + OFF);   // 64MB, aliases xh+w1t (dead after gemm1)

    dim3 g1(INTERM / 32, HID / 32, NEXP);
    tconv_kernel<<<g1, 256, 0, stream>>>(w1, w1t, HID, INTERM);   // w1t[e][i][h]
    dim3 g2(HID / 32, INTERM / 32, NEXP);
    tconv_kernel<<<g2, 256, 0, stream>>>(w2, w2t, INTERM, HID);   // w2t[e][h][i]

    gate_kernel<<<GATE_NB, 256, 0, stream>>>(x, gw, xh, tk_idx, tk_w, part_cnt, part_sumP);
    finalize_kernel<<<1, 256, 0, stream>>>(part_cnt, part_sumP, cnt, offs, cursor,
                                           out + (size_t)T_TOKENS * HID);
    scatter_kernel<<<T_TOKENS / 256, 256, 0, stream>>>(tk_idx, tk_w, offs, cursor,
                                                       row_tok, row_w, tok_row);

    dim3 gg1(INTERM / 128, 64, NEXP);
    gemm1_kernel<<<gg1, 256, 0, stream>>>(xh, w1t, cnt, offs, row_tok, hh);
    dim3 gg2(HID / 128, 64, NEXP);
    gemm2_kernel<<<gg2, 256, 0, stream>>>(hh, w2t, cnt, offs, y);

    combine_kernel<<<T_TOKENS, 256, 0, stream>>>(y, tok_row, tk_w, out);
}